// Round 9
// baseline (807.281 us; speedup 1.0000x reference)
//
#include <hip/hip_runtime.h>
#include <hip/hip_bf16.h>

#define E_ 8
#define H_ 2048
#define I_ 5632
#define B_ 1024
#define K_ 2
#define NROWS (B_*K_)

#define BM 128
#define BK 64
#define MAXT 24           // sum_e ceil(cnt_e/128) <= 16 + 8
#define NKG (H_/BK)       // 32
#define NKD (I_/BK)       // 88
#define NYG (I_/32)       // 176  (gateup BN=32)
#define NYD (H_/64)       // 32   (down BN=64)

typedef __attribute__((ext_vector_type(8))) __bf16 bf16x8;
typedef __attribute__((ext_vector_type(4))) float f32x4;

union BF2 { __bf16 b[2]; uint q; };
union BF4 { __bf16 b[4]; uint2 q; };
union BF8 { __bf16 b[8]; uint4 q; };

#define GLOAD4(dst, ptr) asm volatile("global_load_dwordx4 %0, %1, off" : "=v"(dst) : "v"(ptr))
#define WAITV(N) do { asm volatile("s_waitcnt vmcnt(" #N ")" ::: "memory"); __builtin_amdgcn_sched_barrier(0); } while(0)
#define WAITL()  do { asm volatile("s_waitcnt lgkmcnt(0)" ::: "memory"); __builtin_amdgcn_sched_barrier(0); } while(0)
#define BAR()    __builtin_amdgcn_s_barrier()
#define SB0()    __builtin_amdgcn_sched_barrier(0)

// bank-spread swizzle (verified R8: conflicts 5.46e7 -> 7.8e6)
#define MSK(c) (((c)&7) ^ (((c)>>2)&7))

// ---------------- phase 0: x (f32) -> xb (bf16) ----------------
__global__ void cvtx_kernel(const float* __restrict__ x, __bf16* __restrict__ xb) {
  int i = (blockIdx.x * 256 + threadIdx.x) * 8;
  float4 a = *(const float4*)(x + i);
  float4 b = *(const float4*)(x + i + 4);
  BF8 r;
  r.b[0] = (__bf16)a.x; r.b[1] = (__bf16)a.y; r.b[2] = (__bf16)a.z; r.b[3] = (__bf16)a.w;
  r.b[4] = (__bf16)b.x; r.b[5] = (__bf16)b.y; r.b[6] = (__bf16)b.z; r.b[7] = (__bf16)b.w;
  *(uint4*)(xb + i) = r.q;
}

// ---------------- phase 1: routing + dense tile list ----------------
__global__ void route_kernel(const int* __restrict__ ids,
                             int* __restrict__ counts, int* __restrict__ offsets,
                             int* __restrict__ tlist, int* __restrict__ row_of,
                             int* __restrict__ tile_e, int* __restrict__ tile_m) {
  __shared__ int sc[E_], sp[E_], so[E_];
  int t = threadIdx.x;
  if (t < E_) { sc[t] = 0; sp[t] = 0; }
  __syncthreads();
  for (int idx = t; idx < NROWS; idx += 256) atomicAdd(&sc[ids[idx]], 1);
  __syncthreads();
  if (t == 0) {
    int acc = 0;
    for (int e = 0; e < E_; ++e) { so[e] = acc; acc += sc[e]; }
    int nt = 0;
    for (int e = 0; e < E_; ++e)
      for (int m0 = 0; m0 < sc[e]; m0 += BM) { tile_e[nt] = e; tile_m[nt] = m0; ++nt; }
    for (; nt < MAXT; ++nt) { tile_e[nt] = 0; tile_m[nt] = 0x7FFFFFFF; }
  }
  __syncthreads();
  for (int idx = t; idx < NROWS; idx += 256) {
    int e = ids[idx];
    int slot = atomicAdd(&sp[e], 1);
    int row = so[e] + slot;
    tlist[row] = idx / K_;
    row_of[idx] = row;
  }
  if (t < E_) { counts[t] = sc[t]; offsets[t] = so[t]; }
}

// ---------------- phase 2: gate+up dual GEMM + SiLU (bf16 act) ----------------
// 128x32 tile, 4 waves (2m x 2n). A fragments direct from global (xb is
// L2/L3-resident) — no A LDS. B: 2 matrices reg-staged into 16 KB swizzled
// LDS. One wait (vmcnt(4)) + one barrier per k-step; 12 outstanding steady.
__global__ __launch_bounds__(256, 2) void gateup_kernel(
    const __bf16* __restrict__ xb, const float* __restrict__ gw,
    const float* __restrict__ uw, const int* __restrict__ counts,
    const int* __restrict__ offsets, const int* __restrict__ tlist,
    const int* __restrict__ tile_e, const int* __restrict__ tile_m,
    __bf16* __restrict__ act)
{
  extern __shared__ char smem[];
  char* Bg0 = smem;                 // 4096 each: [32 cols][128 B] swizzled
  char* Bg1 = smem + 4096;
  char* Bu0 = smem + 8192;
  char* Bu1 = smem + 12288;

  const int id = blockIdx.x;                  // [0, 4224)
  const int w  = (id & 7) * 528 + (id >> 3);  // XCD chunking (4224 = 8*528)
  const int tt = w % MAXT;                    // tile-minor: panel sharers adjacent
  const int ny = w / MAXT;                    // [0, 176)
  const int e  = tile_e[tt];
  const int m0 = tile_m[tt];
  const int cnt = counts[e];
  if (m0 >= cnt) return;
  const int off = offsets[e];
  const int n0 = ny * 32;

  const int tid  = threadIdx.x;
  const int lane = tid & 63;
  const int wave = tid >> 6;         // 0..3
  const int wr = (wave >> 1) * 64;   // 0,64
  const int wc = (wave & 1) * 16;    // 0,16

  // ---- A direct-load bases: per lane, 4 token rows, k-chunk by lane>>4
  const __bf16* ab0; const __bf16* ab1; const __bf16* ab2; const __bf16* ab3;
  {
    const __bf16* a[4];
#pragma unroll
    for (int mi = 0; mi < 4; ++mi) {
      int rr = m0 + wr + mi*16 + (lane & 15);
      if (rr >= cnt) rr = cnt - 1;
      int tok = tlist[off + rr];
      a[mi] = xb + (size_t)tok * H_ + ((lane >> 4) * 8);
    }
    ab0=a[0]; ab1=a[1]; ab2=a[2]; ab3=a[3];
  }

  // ---- B staging: thread owns cols 4q..4q+3, k-pair kb,kb+1 (per matrix)
  const int q  = tid & 7;
  const int kr = tid >> 3;           // 0..31
  const int kb = kr * 2;
  const float* pg0 = gw + ((size_t)e*H_ + kb + 0)*I_ + n0 + 4*q;
  const float* pg1 = gw + ((size_t)e*H_ + kb + 1)*I_ + n0 + 4*q;
  const float* pu0 = uw + ((size_t)e*H_ + kb + 0)*I_ + n0 + 4*q;
  const float* pu1 = uw + ((size_t)e*H_ + kb + 1)*I_ + n0 + 4*q;
  const int slot = kr >> 2;
  const int insl = (kr & 3) * 4;
  int bw0, bw1, bw2, bw3;
  {
    int b[4];
#pragma unroll
    for (int i = 0; i < 4; ++i) {
      int c = 4*q + i;
      b[i] = c*128 + ((slot ^ MSK(c)) << 4) + insl;
    }
    bw0=b[0]; bw1=b[1]; bw2=b[2]; bw3=b[3];
  }

  f32x4 vgA_0,vgA_1, vuA_0,vuA_1;    // weight PF set A
  f32x4 vgB_0,vgB_1, vuB_0,vuB_1;    // weight PF set B
  bf16x8 tA_0,tA_1,tA_2,tA_3,tA_4,tA_5,tA_6,tA_7;  // A frags (kk*4+mi)

  f32x4 accg[4], accu[4];
#pragma unroll
  for (int i = 0; i < 4; ++i) {
    accg[i] = (f32x4){0.f,0.f,0.f,0.f};
    accu[i] = (f32x4){0.f,0.f,0.f,0.f};
  }

  auto COMPUTE = [&](const char* Bgp, const char* Bup) {
    {
      const int ks = (lane >> 4);
      const int c0 = wc + (lane & 15);
      const int swb = (ks ^ MSK(c0)) << 4;
      bf16x8 g0 = *(const bf16x8*)(Bgp + c0*128 + swb);
      bf16x8 u0 = *(const bf16x8*)(Bup + c0*128 + swb);
      accg[0] = __builtin_amdgcn_mfma_f32_16x16x32_bf16(tA_0, g0, accg[0], 0,0,0);
      accg[1] = __builtin_amdgcn_mfma_f32_16x16x32_bf16(tA_1, g0, accg[1], 0,0,0);
      accg[2] = __builtin_amdgcn_mfma_f32_16x16x32_bf16(tA_2, g0, accg[2], 0,0,0);
      accg[3] = __builtin_amdgcn_mfma_f32_16x16x32_bf16(tA_3, g0, accg[3], 0,0,0);
      accu[0] = __builtin_amdgcn_mfma_f32_16x16x32_bf16(tA_0, u0, accu[0], 0,0,0);
      accu[1] = __builtin_amdgcn_mfma_f32_16x16x32_bf16(tA_1, u0, accu[1], 0,0,0);
      accu[2] = __builtin_amdgcn_mfma_f32_16x16x32_bf16(tA_2, u0, accu[2], 0,0,0);
      accu[3] = __builtin_amdgcn_mfma_f32_16x16x32_bf16(tA_3, u0, accu[3], 0,0,0);
    }
    {
      const int ks = 4 + (lane >> 4);
      const int c0 = wc + (lane & 15);
      const int swb = (ks ^ MSK(c0)) << 4;
      bf16x8 g1 = *(const bf16x8*)(Bgp + c0*128 + swb);
      bf16x8 u1 = *(const bf16x8*)(Bup + c0*128 + swb);
      accg[0] = __builtin_amdgcn_mfma_f32_16x16x32_bf16(tA_4, g1, accg[0], 0,0,0);
      accg[1] = __builtin_amdgcn_mfma_f32_16x16x32_bf16(tA_5, g1, accg[1], 0,0,0);
      accg[2] = __builtin_amdgcn_mfma_f32_16x16x32_bf16(tA_6, g1, accg[2], 0,0,0);
      accg[3] = __builtin_amdgcn_mfma_f32_16x16x32_bf16(tA_7, g1, accg[3], 0,0,0);
      accu[0] = __builtin_amdgcn_mfma_f32_16x16x32_bf16(tA_4, u1, accu[0], 0,0,0);
      accu[1] = __builtin_amdgcn_mfma_f32_16x16x32_bf16(tA_5, u1, accu[1], 0,0,0);
      accu[2] = __builtin_amdgcn_mfma_f32_16x16x32_bf16(tA_6, u1, accu[2], 0,0,0);
      accu[3] = __builtin_amdgcn_mfma_f32_16x16x32_bf16(tA_7, u1, accu[3], 0,0,0);
    }
  };

#define GU_PF(S, KPF) do { size_t o_ = (size_t)(KPF)*(size_t)BK*(size_t)I_; \
    GLOAD4(vg##S##_0, pg0+o_); GLOAD4(vg##S##_1, pg1+o_); \
    GLOAD4(vu##S##_0, pu0+o_); GLOAD4(vu##S##_1, pu1+o_); } while(0)

#define GU_CVW1(BB, V0, V1, BWI, I) do { BF2 p_; \
    p_.b[0]=(__bf16)V0[I]; p_.b[1]=(__bf16)V1[I]; \
    *(uint*)((BB)+BWI) = p_.q; } while(0)

#define GU_CVW(S, BG, BU) do { \
    GU_CVW1(BG, vg##S##_0, vg##S##_1, bw0, 0); \
    GU_CVW1(BG, vg##S##_0, vg##S##_1, bw1, 1); \
    GU_CVW1(BG, vg##S##_0, vg##S##_1, bw2, 2); \
    GU_CVW1(BG, vg##S##_0, vg##S##_1, bw3, 3); \
    GU_CVW1(BU, vu##S##_0, vu##S##_1, bw0, 0); \
    GU_CVW1(BU, vu##S##_0, vu##S##_1, bw1, 1); \
    GU_CVW1(BU, vu##S##_0, vu##S##_1, bw2, 2); \
    GU_CVW1(BU, vu##S##_0, vu##S##_1, bw3, 3); } while(0)

#define APF(KT) do { size_t e0_ = (size_t)(KT)*64; \
    GLOAD4(tA_0, ab0 + e0_);      GLOAD4(tA_1, ab1 + e0_); \
    GLOAD4(tA_2, ab2 + e0_);      GLOAD4(tA_3, ab3 + e0_); \
    GLOAD4(tA_4, ab0 + e0_ + 32); GLOAD4(tA_5, ab1 + e0_ + 32); \
    GLOAD4(tA_6, ab2 + e0_ + 32); GLOAD4(tA_7, ab3 + e0_ + 32); } while(0)

  // ---- prologue: W(0)->buf0; W(1) set B + A(0) in flight
  GU_PF(A, 0);
  WAITV(0);
  GU_CVW(A, Bg0, Bu0);
  GU_PF(B, 1);          // 4
  APF(0);               // +8 -> 12 (invariant)
  WAITL();
  BAR();

#pragma unroll 1
  for (int kt = 0; kt < NKG; kt += 2) {
    { // even kt: compute buf0; CVW set B -> buf1; refill set A (kt+2)
      int kpf = kt + 2; if (kpf > NKG-1) kpf = NKG-1;
      GU_PF(A, kpf);           // 12 -> 16
      WAITV(4);                // retire W(kt+1)setB + A8(kt); keep W(kt+2)
      COMPUTE(Bg0, Bu0);
      GU_CVW(B, Bg1, Bu1);
      SB0();
      APF(kt + 1);             // -> 12
      WAITL();
      BAR();
    }
    { // odd kt+1: compute buf1; CVW set A -> buf0; refill set B (kt+3)
      int kpf = kt + 3; if (kpf > NKG-1) kpf = NKG-1;
      int ka  = kt + 2; if (ka  > NKG-1) ka  = NKG-1;
      GU_PF(B, kpf);
      WAITV(4);
      COMPUTE(Bg1, Bu1);
      GU_CVW(A, Bg0, Bu0);
      SB0();
      APF(ka);
      WAITL();
      BAR();
    }
  }
  WAITV(0);
  WAITL();

  // ---- epilogue: SiLU(g)*u -> bf16 act
  const int rsub = (lane >> 4) * 4;
  const int csub = lane & 15;
#pragma unroll
  for (int mi = 0; mi < 4; ++mi)
#pragma unroll
    for (int j = 0; j < 4; ++j) {
      int rl = wr + mi*16 + rsub + j;
      if (m0 + rl < cnt) {
        size_t orow = (size_t)(off + m0 + rl) * I_ + n0 + wc + csub;
        float g = accg[mi][j];
        float u = accu[mi][j];
        float sg = g / (1.0f + __expf(-g));
        act[orow] = (__bf16)(sg * u);
      }
    }
#undef GU_PF
#undef GU_CVW
#undef GU_CVW1
#undef APF
}

// ---------------- phase 3: down GEMM -> rowbuf (f32) ----------------
// 128x64 tile. A (act bf16) direct from global; B 16 KB swizzled LDS.
__global__ __launch_bounds__(256, 2) void down_kernel(
    const __bf16* __restrict__ act, const float* __restrict__ dw,
    const int* __restrict__ counts, const int* __restrict__ offsets,
    const int* __restrict__ tile_e, const int* __restrict__ tile_m,
    float* __restrict__ rowbuf)
{
  extern __shared__ char smem[];
  char* Bs0 = smem;                 // 8192 each: [64 cols][128 B]
  char* Bs1 = smem + 8192;

  const int id = blockIdx.x;                  // [0, 768)
  const int w  = (id & 7) * 96 + (id >> 3);   // 768 = 8*96
  const int tt = w % MAXT;
  const int ny = w / MAXT;                    // [0, 32)
  const int e  = tile_e[tt];
  const int m0 = tile_m[tt];
  const int cnt = counts[e];
  if (m0 >= cnt) return;
  const int off = offsets[e];
  const int n0 = ny * 64;

  const int tid  = threadIdx.x;
  const int lane = tid & 63;
  const int wave = tid >> 6;
  const int wr = (wave >> 1) * 64;
  const int wc = (wave & 1) * 32;

  const __bf16* ab0; const __bf16* ab1; const __bf16* ab2; const __bf16* ab3;
  {
    const __bf16* a[4];
#pragma unroll
    for (int mi = 0; mi < 4; ++mi) {
      int rr = m0 + wr + mi*16 + (lane & 15);
      if (rr >= cnt) rr = cnt - 1;
      a[mi] = act + (size_t)(off + rr) * I_ + ((lane >> 4) * 8);
    }
    ab0=a[0]; ab1=a[1]; ab2=a[2]; ab3=a[3];
  }

  // B staging: cols 4cq..4cq+3, k-rows kb..kb+3
  const int cq = tid & 15;
  const int kb = (tid >> 4) * 4;
  const float* pd0 = dw + ((size_t)e*I_ + kb + 0)*H_ + n0 + 4*cq;
  const float* pd1 = dw + ((size_t)e*I_ + kb + 1)*H_ + n0 + 4*cq;
  const float* pd2 = dw + ((size_t)e*I_ + kb + 2)*H_ + n0 + 4*cq;
  const float* pd3 = dw + ((size_t)e*I_ + kb + 3)*H_ + n0 + 4*cq;
  const int slot = kb >> 3;
  const int half = (kb & 4) << 1;
  int bw0, bw1, bw2, bw3;
  {
    int b[4];
#pragma unroll
    for (int i = 0; i < 4; ++i) {
      int c = 4*cq + i;
      b[i] = c*128 + ((slot ^ MSK(c)) << 4) + half;
    }
    bw0=b[0]; bw1=b[1]; bw2=b[2]; bw3=b[3];
  }

  f32x4 vdA_0,vdA_1,vdA_2,vdA_3;
  f32x4 vdB_0,vdB_1,vdB_2,vdB_3;
  bf16x8 tA_0,tA_1,tA_2,tA_3,tA_4,tA_5,tA_6,tA_7;

  f32x4 acc[4][2];
#pragma unroll
  for (int i = 0; i < 4; ++i)
#pragma unroll
    for (int j = 0; j < 2; ++j) acc[i][j] = (f32x4){0.f,0.f,0.f,0.f};

  auto COMPUTE = [&](const char* Bp) {
    {
      const int ks = (lane >> 4);
      const int c0 = wc + (lane & 15);
      const int swb0 = (ks ^ MSK(c0)) << 4;
      const int swb1 = swb0 ^ (4 << 4);
      bf16x8 b0 = *(const bf16x8*)(Bp + c0*128 + swb0);
      bf16x8 b1 = *(const bf16x8*)(Bp + (c0+16)*128 + swb1);
      acc[0][0] = __builtin_amdgcn_mfma_f32_16x16x32_bf16(tA_0, b0, acc[0][0], 0,0,0);
      acc[1][0] = __builtin_amdgcn_mfma_f32_16x16x32_bf16(tA_1, b0, acc[1][0], 0,0,0);
      acc[2][0] = __builtin_amdgcn_mfma_f32_16x16x32_bf16(tA_2, b0, acc[2][0], 0,0,0);
      acc[3][0] = __builtin_amdgcn_mfma_f32_16x16x32_bf16(tA_3, b0, acc[3][0], 0,0,0);
      acc[0][1] = __builtin_amdgcn_mfma_f32_16x16x32_bf16(tA_0, b1, acc[0][1], 0,0,0);
      acc[1][1] = __builtin_amdgcn_mfma_f32_16x16x32_bf16(tA_1, b1, acc[1][1], 0,0,0);
      acc[2][1] = __builtin_amdgcn_mfma_f32_16x16x32_bf16(tA_2, b1, acc[2][1], 0,0,0);
      acc[3][1] = __builtin_amdgcn_mfma_f32_16x16x32_bf16(tA_3, b1, acc[3][1], 0,0,0);
    }
    {
      const int ks = 4 + (lane >> 4);
      const int c0 = wc + (lane & 15);
      const int swb0 = (ks ^ MSK(c0)) << 4;
      const int swb1 = swb0 ^ (4 << 4);
      bf16x8 b0 = *(const bf16x8*)(Bp + c0*128 + swb0);
      bf16x8 b1 = *(const bf16x8*)(Bp + (c0+16)*128 + swb1);
      acc[0][0] = __builtin_amdgcn_mfma_f32_16x16x32_bf16(tA_4, b0, acc[0][0], 0,0,0);
      acc[1][0] = __builtin_amdgcn_mfma_f32_16x16x32_bf16(tA_5, b0, acc[1][0], 0,0,0);
      acc[2][0] = __builtin_amdgcn_mfma_f32_16x16x32_bf16(tA_6, b0, acc[2][0], 0,0,0);
      acc[3][0] = __builtin_amdgcn_mfma_f32_16x16x32_bf16(tA_7, b0, acc[3][0], 0,0,0);
      acc[0][1] = __builtin_amdgcn_mfma_f32_16x16x32_bf16(tA_4, b1, acc[0][1], 0,0,0);
      acc[1][1] = __builtin_amdgcn_mfma_f32_16x16x32_bf16(tA_5, b1, acc[1][1], 0,0,0);
      acc[2][1] = __builtin_amdgcn_mfma_f32_16x16x32_bf16(tA_6, b1, acc[2][1], 0,0,0);
      acc[3][1] = __builtin_amdgcn_mfma_f32_16x16x32_bf16(tA_7, b1, acc[3][1], 0,0,0);
    }
  };

#define DN_PF(S, KPF) do { size_t o_ = (size_t)(KPF)*(size_t)BK*(size_t)H_; \
    GLOAD4(vd##S##_0, pd0+o_); GLOAD4(vd##S##_1, pd1+o_); \
    GLOAD4(vd##S##_2, pd2+o_); GLOAD4(vd##S##_3, pd3+o_); } while(0)

#define DN_CVW1(BB, V0, V1, V2, V3, BWI, I) do { BF4 p_; \
    p_.b[0]=(__bf16)V0[I]; p_.b[1]=(__bf16)V1[I]; p_.b[2]=(__bf16)V2[I]; p_.b[3]=(__bf16)V3[I]; \
    *(uint2*)((BB)+BWI) = p_.q; } while(0)

#define DN_CVW(S, BB) do { \
    DN_CVW1(BB, vd##S##_0, vd##S##_1, vd##S##_2, vd##S##_3, bw0, 0); \
    DN_CVW1(BB, vd##S##_0, vd##S##_1, vd##S##_2, vd##S##_3, bw1, 1); \
    DN_CVW1(BB, vd##S##_0, vd##S##_1, vd##S##_2, vd##S##_3, bw2, 2); \
    DN_CVW1(BB, vd##S##_0, vd##S##_1, vd##S##_2, vd##S##_3, bw3, 3); } while(0)

#define APF(KT) do { size_t e0_ = (size_t)(KT)*64; \
    GLOAD4(tA_0, ab0 + e0_);      GLOAD4(tA_1, ab1 + e0_); \
    GLOAD4(tA_2, ab2 + e0_);      GLOAD4(tA_3, ab3 + e0_); \
    GLOAD4(tA_4, ab0 + e0_ + 32); GLOAD4(tA_5, ab1 + e0_ + 32); \
    GLOAD4(tA_6, ab2 + e0_ + 32); GLOAD4(tA_7, ab3 + e0_ + 32); } while(0)

  DN_PF(A, 0);
  WAITV(0);
  DN_CVW(A, Bs0);
  DN_PF(B, 1);          // 4
  APF(0);               // +8 -> 12
  WAITL();
  BAR();

#pragma unroll 1
  for (int kt = 0; kt < NKD; kt += 2) {
    {
      int kpf = kt + 2; if (kpf > NKD-1) kpf = NKD-1;
      DN_PF(A, kpf);           // -> 16
      WAITV(4);                // retire W(kt+1) + A8(kt)
      COMPUTE(Bs0);
      DN_CVW(B, Bs1);
      SB0();
      APF(kt + 1);             // -> 12
      WAITL();
      BAR();
    }
    {
      int kpf = kt + 3; if (kpf > NKD-1) kpf = NKD-1;
      int ka  = kt + 2; if (ka  > NKD-1) ka  = NKD-1;
      DN_PF(B, kpf);
      WAITV(4);
      COMPUTE(Bs1);
      DN_CVW(A, Bs0);
      SB0();
      APF(ka);
      WAITL();
      BAR();
    }
  }
  WAITV(0);
  WAITL();

  const int rsub = (lane >> 4) * 4;
  const int csub = lane & 15;
#pragma unroll
  for (int mi = 0; mi < 4; ++mi)
#pragma unroll
    for (int j = 0; j < 4; ++j) {
      int rl = wr + mi*16 + rsub + j;
      if (m0 + rl < cnt) {
        size_t orow = (size_t)(off + m0 + rl) * H_ + n0 + wc + csub;
#pragma unroll
        for (int cg = 0; cg < 2; ++cg)
          rowbuf[orow + cg*16] = acc[mi][cg][j];
      }
    }
#undef DN_PF
#undef DN_CVW
#undef DN_CVW1
#undef APF
}

// ---------------- phase 4: weighted combine ----------------
__global__ void combine_kernel(const float* __restrict__ ew, const int* __restrict__ row_of,
                               const float* __restrict__ rowbuf, float* __restrict__ out) {
  int idx = blockIdx.x * 256 + threadIdx.x;   // over B_*H_/4
  int t  = idx >> 9;                          // H_/4 = 512
  int h4 = idx & 511;
  float w0 = ew[t*2+0], w1 = ew[t*2+1];
  int r0 = row_of[t*2+0], r1 = row_of[t*2+1];
  float4 a = *(const float4*)(rowbuf + (size_t)r0*H_ + h4*4);
  float4 b = *(const float4*)(rowbuf + (size_t)r1*H_ + h4*4);
  float4 o;
  o.x = w0*a.x + w1*b.x; o.y = w0*a.y + w1*b.y;
  o.z = w0*a.z + w1*b.z; o.w = w0*a.w + w1*b.w;
  *(float4*)(out + (size_t)idx*4) = o;
}

extern "C" void kernel_launch(void* const* d_in, const int* in_sizes, int n_in,
                              void* d_out, int out_size, void* d_ws, size_t ws_size,
                              hipStream_t stream) {
  const float* x   = (const float*)d_in[0];
  const int*   ids = (const int*)d_in[1];
  const float* ew  = (const float*)d_in[2];
  const float* gw  = (const float*)d_in[3];
  const float* uw  = (const float*)d_in[4];
  const float* dwn = (const float*)d_in[5];
  float* out = (float*)d_out;

  char* ws = (char*)d_ws;
  int* counts  = (int*)ws;          // 8
  int* offsets = counts + 8;        // 8
  int* tlist   = offsets + 8;       // NROWS
  int* row_of  = tlist + NROWS;     // NROWS
  int* tile_e  = row_of + NROWS;    // MAXT
  int* tile_m  = tile_e + MAXT;     // MAXT
  __bf16* xb   = (__bf16*)(ws + 32768);
  __bf16* act  = (__bf16*)(ws + 32768 + (size_t)B_*H_*2);
  float* rowbuf = (float*)(ws + 32768 + (size_t)B_*H_*2 + (size_t)NROWS*I_*2);

  hipFuncSetAttribute(reinterpret_cast<const void*>(&gateup_kernel),
                      hipFuncAttributeMaxDynamicSharedMemorySize, 16384);
  hipFuncSetAttribute(reinterpret_cast<const void*>(&down_kernel),
                      hipFuncAttributeMaxDynamicSharedMemorySize, 16384);

  cvtx_kernel<<<B_*H_/(256*8), 256, 0, stream>>>(x, xb);
  route_kernel<<<1, 256, 0, stream>>>(ids, counts, offsets, tlist, row_of, tile_e, tile_m);

  gateup_kernel<<<MAXT*NYG, 256, 16384, stream>>>(xb, gw, uw, counts, offsets, tlist,
                                                  tile_e, tile_m, act);

  down_kernel<<<MAXT*NYD, 256, 16384, stream>>>(act, dwn, counts, offsets,
                                                tile_e, tile_m, rowbuf);

  combine_kernel<<<(B_*H_/4)/256, 256, 0, stream>>>(ew, row_of, rowbuf, out);
}

// Round 10
// 428.773 us; speedup vs baseline: 1.8828x; 1.8828x over previous
//
#include <hip/hip_runtime.h>
#include <hip/hip_bf16.h>

#define E_ 8
#define H_ 2048
#define I_ 5632
#define B_ 1024
#define K_ 2
#define NROWS (B_*K_)

#define BM 128
#define BN 64
#define BK 64
#define MAXT 24           // sum_e ceil(cnt_e/128) <= 16 + 8
#define NKG (H_/BK)       // 32
#define NKD (I_/BK)       // 88
#define NYG (I_/BN)       // 88
#define NYD (H_/BN)       // 32

typedef __attribute__((ext_vector_type(8))) __bf16 bf16x8;
typedef __attribute__((ext_vector_type(4))) float f32x4;

union BF4 { __bf16 b[4]; uint2 q; };
union BF8 { __bf16 b[8]; uint4 q; };

__device__ __forceinline__ void gld_lds16(const void* g, void* l) {
  __builtin_amdgcn_global_load_lds(
      (const __attribute__((address_space(1))) void*)g,
      (__attribute__((address_space(3))) void*)l, 16, 0, 0);
}

#define GLOAD4(dst, ptr) asm volatile("global_load_dwordx4 %0, %1, off" : "=v"(dst) : "v"(ptr))
#define WAITV(N) do { asm volatile("s_waitcnt vmcnt(" #N ")" ::: "memory"); __builtin_amdgcn_sched_barrier(0); } while(0)
#define WAITL()  do { asm volatile("s_waitcnt lgkmcnt(0)" ::: "memory"); __builtin_amdgcn_sched_barrier(0); } while(0)
#define BAR()    __builtin_amdgcn_s_barrier()

// bank-spread swizzle (verified R8: conflicts 5.46e7 -> 7.8e6)
#define MSK(c) (((c)&7) ^ (((c)>>2)&7))

// ---------------- phase 0: x (f32) -> xb (bf16) ----------------
__global__ void cvtx_kernel(const float* __restrict__ x, __bf16* __restrict__ xb) {
  int i = (blockIdx.x * 256 + threadIdx.x) * 8;
  float4 a = *(const float4*)(x + i);
  float4 b = *(const float4*)(x + i + 4);
  BF8 r;
  r.b[0] = (__bf16)a.x; r.b[1] = (__bf16)a.y; r.b[2] = (__bf16)a.z; r.b[3] = (__bf16)a.w;
  r.b[4] = (__bf16)b.x; r.b[5] = (__bf16)b.y; r.b[6] = (__bf16)b.z; r.b[7] = (__bf16)b.w;
  *(uint4*)(xb + i) = r.q;
}

// ---------------- phase 1: routing + dense tile list ----------------
__global__ void route_kernel(const int* __restrict__ ids,
                             int* __restrict__ counts, int* __restrict__ offsets,
                             int* __restrict__ tlist, int* __restrict__ row_of,
                             int* __restrict__ tile_e, int* __restrict__ tile_m) {
  __shared__ int sc[E_], sp[E_], so[E_];
  int t = threadIdx.x;
  if (t < E_) { sc[t] = 0; sp[t] = 0; }
  __syncthreads();
  for (int idx = t; idx < NROWS; idx += 256) atomicAdd(&sc[ids[idx]], 1);
  __syncthreads();
  if (t == 0) {
    int acc = 0;
    for (int e = 0; e < E_; ++e) { so[e] = acc; acc += sc[e]; }
    int nt = 0;
    for (int e = 0; e < E_; ++e)
      for (int m0 = 0; m0 < sc[e]; m0 += BM) { tile_e[nt] = e; tile_m[nt] = m0; ++nt; }
    for (; nt < MAXT; ++nt) { tile_e[nt] = 0; tile_m[nt] = 0x7FFFFFFF; }
  }
  __syncthreads();
  for (int idx = t; idx < NROWS; idx += 256) {
    int e = ids[idx];
    int slot = atomicAdd(&sp[e], 1);
    int row = so[e] + slot;
    tlist[row] = idx / K_;
    row_of[idx] = row;
  }
  if (t < E_) { counts[t] = sc[t]; offsets[t] = so[t]; }
}

// ---------------- phase 2: gate+up dual GEMM + SiLU (bf16 act) ----------------
// 48 KB LDS (A single-buffered 16K + B dbuf 2x2x8K) -> 3 blocks/CU.
// Two barriers per k-step: consumption fence (A overwrite) + completion fence
// (cross-wave gld_lds visibility). Counted vmcnt; weight regs 1 phase deep.
__global__ __launch_bounds__(256, 3) void gateup_kernel(
    const __bf16* __restrict__ xb, const float* __restrict__ gw,
    const float* __restrict__ uw, const int* __restrict__ counts,
    const int* __restrict__ offsets, const int* __restrict__ tlist,
    const int* __restrict__ tile_e, const int* __restrict__ tile_m,
    __bf16* __restrict__ act)
{
  extern __shared__ char smem[];
  char* As  = smem;                 // 16384 (128 rows x 128B, swizzled), single buf
  char* Bg0 = smem + 16384;         // 8192 each (64 cols x 128B, swizzled)
  char* Bg1 = smem + 24576;
  char* Bu0 = smem + 32768;
  char* Bu1 = smem + 40960;

  const int id = blockIdx.x;                  // [0, 2112)
  const int w  = (id & 7) * 264 + (id >> 3);  // XCD chunking (2112 = 8*264)
  const int tt = w % MAXT;                    // panel sharers adjacent -> same XCD
  const int ny = w / MAXT;                    // [0, 88)
  const int e  = tile_e[tt];
  const int m0 = tile_m[tt];
  const int cnt = counts[e];
  if (m0 >= cnt) return;
  const int off = offsets[e];
  const int n0 = ny * BN;

  const int tid  = threadIdx.x;
  const int lane = tid & 63;
  const int wave = tid >> 6;         // 0..3
  const int wr = (wave >> 1) * 64;   // 0,64
  const int wc = (wave & 1) * 32;    // 0,32

  // ---- A staging: 4 granules/thread, LDS linear, source slot-swizzled
  const __bf16* asrc0; const __bf16* asrc1; const __bf16* asrc2; const __bf16* asrc3;
  int ad0, ad1, ad2, ad3;
  {
    const __bf16* s[4]; int d[4];
#pragma unroll
    for (int i = 0; i < 4; ++i) {
      int f = i*256 + tid;
      int r = f >> 3, cs = f & 7;
      int rr = m0 + r; if (rr >= cnt) rr = cnt - 1;
      int tok = tlist[off + rr];
      s[i] = xb + (size_t)tok * H_ + ((cs ^ (r & 7)) << 3);
      d[i] = f * 16;
    }
    asrc0=s[0]; asrc1=s[1]; asrc2=s[2]; asrc3=s[3];
    ad0=d[0]; ad1=d[1]; ad2=d[2]; ad3=d[3];
  }

  // ---- B staging: thread owns cols 4cq..4cq+3, k-rows kb..kb+3 (dwordx4)
  const int cq = tid & 15;
  const int kb = (tid >> 4) * 4;     // 0..60
  const float* pg0 = gw + ((size_t)e*H_ + kb + 0)*I_ + n0 + 4*cq;
  const float* pg1 = gw + ((size_t)e*H_ + kb + 1)*I_ + n0 + 4*cq;
  const float* pg2 = gw + ((size_t)e*H_ + kb + 2)*I_ + n0 + 4*cq;
  const float* pg3 = gw + ((size_t)e*H_ + kb + 3)*I_ + n0 + 4*cq;
  const float* pu0 = uw + ((size_t)e*H_ + kb + 0)*I_ + n0 + 4*cq;
  const float* pu1 = uw + ((size_t)e*H_ + kb + 1)*I_ + n0 + 4*cq;
  const float* pu2 = uw + ((size_t)e*H_ + kb + 2)*I_ + n0 + 4*cq;
  const float* pu3 = uw + ((size_t)e*H_ + kb + 3)*I_ + n0 + 4*cq;
  const int slot = kb >> 3;
  const int half = (kb & 4) << 1;    // 0 or 8
  int bw0, bw1, bw2, bw3;
  {
    int b[4];
#pragma unroll
    for (int i = 0; i < 4; ++i) {
      int c = 4*cq + i;
      b[i] = c*128 + ((slot ^ MSK(c)) << 4) + half;
    }
    bw0=b[0]; bw1=b[1]; bw2=b[2]; bw3=b[3];
  }

  f32x4 vgA_0,vgA_1,vgA_2,vgA_3, vuA_0,vuA_1,vuA_2,vuA_3;
  f32x4 vgB_0,vgB_1,vgB_2,vgB_3, vuB_0,vuB_1,vuB_2,vuB_3;

  f32x4 accg[4][2], accu[4][2];
#pragma unroll
  for (int i = 0; i < 4; ++i)
#pragma unroll
    for (int j = 0; j < 2; ++j) {
      accg[i][j] = (f32x4){0.f,0.f,0.f,0.f};
      accu[i][j] = (f32x4){0.f,0.f,0.f,0.f};
    }

  auto COMPUTE = [&](const char* Bgb, const char* Bub) {
    __builtin_amdgcn_s_setprio(1);
#pragma unroll
    for (int kk = 0; kk < 2; ++kk) {
      const int ks = kk*4 + (lane >> 4);
      const int r0 = wr + (lane & 15);
      const int swa = (ks ^ (r0 & 7)) << 4;
      bf16x8 a0 = *(const bf16x8*)(As + (r0 +  0)*128 + swa);
      bf16x8 a1 = *(const bf16x8*)(As + (r0 + 16)*128 + swa);
      bf16x8 a2 = *(const bf16x8*)(As + (r0 + 32)*128 + swa);
      bf16x8 a3 = *(const bf16x8*)(As + (r0 + 48)*128 + swa);
      const int c0 = wc + (lane & 15);
      const int swb0 = (ks ^ MSK(c0)) << 4;
      const int swb1 = swb0 ^ (4 << 4);     // MSK(c+16) = MSK(c) ^ 4
      bf16x8 g0 = *(const bf16x8*)(Bgb + c0*128 + swb0);
      bf16x8 g1 = *(const bf16x8*)(Bgb + (c0+16)*128 + swb1);
      bf16x8 u0 = *(const bf16x8*)(Bub + c0*128 + swb0);
      bf16x8 u1 = *(const bf16x8*)(Bub + (c0+16)*128 + swb1);
      accg[0][0] = __builtin_amdgcn_mfma_f32_16x16x32_bf16(a0, g0, accg[0][0], 0,0,0);
      accg[1][0] = __builtin_amdgcn_mfma_f32_16x16x32_bf16(a1, g0, accg[1][0], 0,0,0);
      accg[2][0] = __builtin_amdgcn_mfma_f32_16x16x32_bf16(a2, g0, accg[2][0], 0,0,0);
      accg[3][0] = __builtin_amdgcn_mfma_f32_16x16x32_bf16(a3, g0, accg[3][0], 0,0,0);
      accg[0][1] = __builtin_amdgcn_mfma_f32_16x16x32_bf16(a0, g1, accg[0][1], 0,0,0);
      accg[1][1] = __builtin_amdgcn_mfma_f32_16x16x32_bf16(a1, g1, accg[1][1], 0,0,0);
      accg[2][1] = __builtin_amdgcn_mfma_f32_16x16x32_bf16(a2, g1, accg[2][1], 0,0,0);
      accg[3][1] = __builtin_amdgcn_mfma_f32_16x16x32_bf16(a3, g1, accg[3][1], 0,0,0);
      accu[0][0] = __builtin_amdgcn_mfma_f32_16x16x32_bf16(a0, u0, accu[0][0], 0,0,0);
      accu[1][0] = __builtin_amdgcn_mfma_f32_16x16x32_bf16(a1, u0, accu[1][0], 0,0,0);
      accu[2][0] = __builtin_amdgcn_mfma_f32_16x16x32_bf16(a2, u0, accu[2][0], 0,0,0);
      accu[3][0] = __builtin_amdgcn_mfma_f32_16x16x32_bf16(a3, u0, accu[3][0], 0,0,0);
      accu[0][1] = __builtin_amdgcn_mfma_f32_16x16x32_bf16(a0, u1, accu[0][1], 0,0,0);
      accu[1][1] = __builtin_amdgcn_mfma_f32_16x16x32_bf16(a1, u1, accu[1][1], 0,0,0);
      accu[2][1] = __builtin_amdgcn_mfma_f32_16x16x32_bf16(a2, u1, accu[2][1], 0,0,0);
      accu[3][1] = __builtin_amdgcn_mfma_f32_16x16x32_bf16(a3, u1, accu[3][1], 0,0,0);
    }
    __builtin_amdgcn_s_setprio(0);
  };

#define GU_PF(S, KPF) do { size_t o_ = (size_t)(KPF)*(size_t)BK*(size_t)I_; \
    GLOAD4(vg##S##_0, pg0+o_); GLOAD4(vu##S##_0, pu0+o_); \
    GLOAD4(vg##S##_1, pg1+o_); GLOAD4(vu##S##_1, pu1+o_); \
    GLOAD4(vg##S##_2, pg2+o_); GLOAD4(vu##S##_2, pu2+o_); \
    GLOAD4(vg##S##_3, pg3+o_); GLOAD4(vu##S##_3, pu3+o_); } while(0)

#define GU_CVW1(BG, V0, V1, V2, V3, BWI, I) do { BF4 p_; \
    p_.b[0]=(__bf16)V0[I]; p_.b[1]=(__bf16)V1[I]; p_.b[2]=(__bf16)V2[I]; p_.b[3]=(__bf16)V3[I]; \
    *(uint2*)((BG)+BWI) = p_.q; } while(0)

#define GU_CVW(S, BG, BU) do { \
    GU_CVW1(BG, vg##S##_0, vg##S##_1, vg##S##_2, vg##S##_3, bw0, 0); \
    GU_CVW1(BG, vg##S##_0, vg##S##_1, vg##S##_2, vg##S##_3, bw1, 1); \
    GU_CVW1(BG, vg##S##_0, vg##S##_1, vg##S##_2, vg##S##_3, bw2, 2); \
    GU_CVW1(BG, vg##S##_0, vg##S##_1, vg##S##_2, vg##S##_3, bw3, 3); \
    GU_CVW1(BU, vu##S##_0, vu##S##_1, vu##S##_2, vu##S##_3, bw0, 0); \
    GU_CVW1(BU, vu##S##_0, vu##S##_1, vu##S##_2, vu##S##_3, bw1, 1); \
    GU_CVW1(BU, vu##S##_0, vu##S##_1, vu##S##_2, vu##S##_3, bw2, 2); \
    GU_CVW1(BU, vu##S##_0, vu##S##_1, vu##S##_2, vu##S##_3, bw3, 3); } while(0)

#define GU_GLDA(KPF) do { size_t k_ = (size_t)(KPF)*(size_t)BK; \
    gld_lds16(asrc0 + k_, As+ad0); gld_lds16(asrc1 + k_, As+ad1); \
    gld_lds16(asrc2 + k_, As+ad2); gld_lds16(asrc3 + k_, As+ad3); } while(0)

  // ---- prologue: B(0)->buf0; A(0)+W(1) in flight; fences
  GU_PF(A, 0);          // 8
  WAITV(0);
  GU_CVW(A, Bg0, Bu0);
  GU_GLDA(0);           // 4 (glda oldest)
  GU_PF(B, 1);          // +8 = 12
  WAITV(8);             // own glda(0) done
  WAITL();
  BAR();                // all waves' glda(0) done + B(0) visible

#pragma unroll 1
  for (int kt = 0; kt < NKG; kt += 2) {
    { // even kt: compute A+buf0; weights set B -> buf1; A(kt+1), W(kt+2)
      int kpf = kt + 2; if (kpf > NKG-1) kpf = NKG-1;
      int ka  = kt + 1; if (ka  > NKG-1) ka  = NKG-1;
      COMPUTE(Bg0, Bu0);
      WAITV(0);                    // W(kt+1) regs ready (issued 1 phase ago)
      GU_CVW(B, Bg1, Bu1);
      WAITL();
      BAR();                       // A(kt) consumed by all; B(kt+1) visible
      GU_GLDA(ka);                 // 4
      GU_PF(A, kpf);               // +8 = 12
      WAITV(8);                    // own glda(kt+1) done
      BAR();                       // all waves' glda done -> A(kt+1) ready
    }
    { // odd kt+1: mirror
      int kpf = kt + 3; if (kpf > NKG-1) kpf = NKG-1;
      int ka  = kt + 2; if (ka  > NKG-1) ka  = NKG-1;
      COMPUTE(Bg1, Bu1);
      WAITV(0);
      GU_CVW(A, Bg0, Bu0);
      WAITL();
      BAR();
      GU_GLDA(ka);
      GU_PF(B, kpf);
      WAITV(8);
      BAR();
    }
  }
  WAITV(0);
  WAITL();

  // ---- epilogue: SiLU(g)*u -> bf16 act
  const int rsub = (lane >> 4) * 4;
  const int csub = lane & 15;
#pragma unroll
  for (int mi = 0; mi < 4; ++mi)
#pragma unroll
    for (int j = 0; j < 4; ++j) {
      int rl = wr + mi*16 + rsub + j;
      if (m0 + rl < cnt) {
        size_t orow = (size_t)(off + m0 + rl) * I_ + n0 + wc + csub;
#pragma unroll
        for (int cg = 0; cg < 2; ++cg) {
          float g = accg[mi][cg][j];
          float u = accu[mi][cg][j];
          float sg = g / (1.0f + __expf(-g));
          act[orow + cg*16] = (__bf16)(sg * u);
        }
      }
    }
#undef GU_PF
#undef GU_CVW
#undef GU_CVW1
#undef GU_GLDA
}

// ---------------- phase 3: down GEMM -> rowbuf (f32) ----------------
// R8-proven: 48 KB LDS -> 3 blocks/CU. Steady outstanding 8 (PF:4 + GLDA:4).
__global__ __launch_bounds__(256, 3) void down_kernel(
    const __bf16* __restrict__ act, const float* __restrict__ dw,
    const int* __restrict__ counts, const int* __restrict__ offsets,
    const int* __restrict__ tile_e, const int* __restrict__ tile_m,
    float* __restrict__ rowbuf)
{
  extern __shared__ char smem[];
  char* As0 = smem;
  char* As1 = smem + 16384;
  char* Bs0 = smem + 32768;
  char* Bs1 = smem + 40960;

  const int id = blockIdx.x;                  // [0, 768)
  const int w  = (id & 7) * 96 + (id >> 3);   // 768 = 8*96
  const int tt = w % MAXT;
  const int ny = w / MAXT;                    // [0, 32)
  const int e  = tile_e[tt];
  const int m0 = tile_m[tt];
  const int cnt = counts[e];
  if (m0 >= cnt) return;
  const int off = offsets[e];
  const int n0 = ny * BN;

  const int tid  = threadIdx.x;
  const int lane = tid & 63;
  const int wave = tid >> 6;
  const int wr = (wave >> 1) * 64;
  const int wc = (wave & 1) * 32;

  const __bf16* asrc0; const __bf16* asrc1; const __bf16* asrc2; const __bf16* asrc3;
  int ad0, ad1, ad2, ad3;
  {
    const __bf16* s[4]; int d[4];
#pragma unroll
    for (int i = 0; i < 4; ++i) {
      int f = i*256 + tid;
      int r = f >> 3, cs = f & 7;
      int rr = m0 + r; if (rr >= cnt) rr = cnt - 1;
      s[i] = act + (size_t)(off + rr) * I_ + ((cs ^ (r & 7)) << 3);
      d[i] = f * 16;
    }
    asrc0=s[0]; asrc1=s[1]; asrc2=s[2]; asrc3=s[3];
    ad0=d[0]; ad1=d[1]; ad2=d[2]; ad3=d[3];
  }

  const int cq = tid & 15;
  const int kb = (tid >> 4) * 4;
  const float* pd0 = dw + ((size_t)e*I_ + kb + 0)*H_ + n0 + 4*cq;
  const float* pd1 = dw + ((size_t)e*I_ + kb + 1)*H_ + n0 + 4*cq;
  const float* pd2 = dw + ((size_t)e*I_ + kb + 2)*H_ + n0 + 4*cq;
  const float* pd3 = dw + ((size_t)e*I_ + kb + 3)*H_ + n0 + 4*cq;
  const int slot = kb >> 3;
  const int half = (kb & 4) << 1;
  int bw0, bw1, bw2, bw3;
  {
    int b[4];
#pragma unroll
    for (int i = 0; i < 4; ++i) {
      int c = 4*cq + i;
      b[i] = c*128 + ((slot ^ MSK(c)) << 4) + half;
    }
    bw0=b[0]; bw1=b[1]; bw2=b[2]; bw3=b[3];
  }

  f32x4 vdA_0,vdA_1,vdA_2,vdA_3;
  f32x4 vdB_0,vdB_1,vdB_2,vdB_3;

  f32x4 acc[4][2];
#pragma unroll
  for (int i = 0; i < 4; ++i)
#pragma unroll
    for (int j = 0; j < 2; ++j) acc[i][j] = (f32x4){0.f,0.f,0.f,0.f};

  auto COMPUTE = [&](const char* Ab, const char* Bb) {
    __builtin_amdgcn_s_setprio(1);
#pragma unroll
    for (int kk = 0; kk < 2; ++kk) {
      const int ks = kk*4 + (lane >> 4);
      const int r0 = wr + (lane & 15);
      const int swa = (ks ^ (r0 & 7)) << 4;
      bf16x8 a0 = *(const bf16x8*)(Ab + (r0 +  0)*128 + swa);
      bf16x8 a1 = *(const bf16x8*)(Ab + (r0 + 16)*128 + swa);
      bf16x8 a2 = *(const bf16x8*)(Ab + (r0 + 32)*128 + swa);
      bf16x8 a3 = *(const bf16x8*)(Ab + (r0 + 48)*128 + swa);
      const int c0 = wc + (lane & 15);
      const int swb0 = (ks ^ MSK(c0)) << 4;
      const int swb1 = swb0 ^ (4 << 4);
      bf16x8 b0 = *(const bf16x8*)(Bb + c0*128 + swb0);
      bf16x8 b1 = *(const bf16x8*)(Bb + (c0+16)*128 + swb1);
      acc[0][0] = __builtin_amdgcn_mfma_f32_16x16x32_bf16(a0, b0, acc[0][0], 0,0,0);
      acc[1][0] = __builtin_amdgcn_mfma_f32_16x16x32_bf16(a1, b0, acc[1][0], 0,0,0);
      acc[2][0] = __builtin_amdgcn_mfma_f32_16x16x32_bf16(a2, b0, acc[2][0], 0,0,0);
      acc[3][0] = __builtin_amdgcn_mfma_f32_16x16x32_bf16(a3, b0, acc[3][0], 0,0,0);
      acc[0][1] = __builtin_amdgcn_mfma_f32_16x16x32_bf16(a0, b1, acc[0][1], 0,0,0);
      acc[1][1] = __builtin_amdgcn_mfma_f32_16x16x32_bf16(a1, b1, acc[1][1], 0,0,0);
      acc[2][1] = __builtin_amdgcn_mfma_f32_16x16x32_bf16(a2, b1, acc[2][1], 0,0,0);
      acc[3][1] = __builtin_amdgcn_mfma_f32_16x16x32_bf16(a3, b1, acc[3][1], 0,0,0);
    }
    __builtin_amdgcn_s_setprio(0);
  };

#define DN_PF(S, KPF) do { size_t o_ = (size_t)(KPF)*(size_t)BK*(size_t)H_; \
    GLOAD4(vd##S##_0, pd0+o_); GLOAD4(vd##S##_1, pd1+o_); \
    GLOAD4(vd##S##_2, pd2+o_); GLOAD4(vd##S##_3, pd3+o_); } while(0)

#define DN_CVW1(BB, V0, V1, V2, V3, BWI, I) do { BF4 p_; \
    p_.b[0]=(__bf16)V0[I]; p_.b[1]=(__bf16)V1[I]; p_.b[2]=(__bf16)V2[I]; p_.b[3]=(__bf16)V3[I]; \
    *(uint2*)((BB)+BWI) = p_.q; } while(0)

#define DN_CVW(S, BB) do { \
    DN_CVW1(BB, vd##S##_0, vd##S##_1, vd##S##_2, vd##S##_3, bw0, 0); \
    DN_CVW1(BB, vd##S##_0, vd##S##_1, vd##S##_2, vd##S##_3, bw1, 1); \
    DN_CVW1(BB, vd##S##_0, vd##S##_1, vd##S##_2, vd##S##_3, bw2, 2); \
    DN_CVW1(BB, vd##S##_0, vd##S##_1, vd##S##_2, vd##S##_3, bw3, 3); } while(0)

#define DN_GLDA(DST, KPF) do { size_t k_ = (size_t)(KPF)*(size_t)BK; \
    gld_lds16(asrc0 + k_, (DST)+ad0); gld_lds16(asrc1 + k_, (DST)+ad1); \
    gld_lds16(asrc2 + k_, (DST)+ad2); gld_lds16(asrc3 + k_, (DST)+ad3); } while(0)

  DN_PF(A, 0);          // 4
  DN_GLDA(As0, 0);      // -> 8
  WAITV(4);             // drain PF(0)
  DN_CVW(A, Bs0);
  DN_PF(B, 1);          // -> 8
  DN_GLDA(As1, 1);      // -> 12
  WAITV(8);             // drain GLDA(0); PF(1)+GLDA(1)=8 left
  WAITL();
  BAR();

#pragma unroll 1
  for (int kt = 0; kt < NKD; kt += 2) {
    {
      int kpf = kt + 2; if (kpf > NKD-1) kpf = NKD-1;
      DN_PF(A, kpf);               // -> 12
      COMPUTE(As0, Bs0);
      WAITV(8);                    // drain PF_B(kt+1)
      DN_CVW(B, Bs1);
      WAITV(4);                    // drain GLDA(kt+1)
      WAITL();
      BAR();
      DN_GLDA(As0, kpf);           // -> 8
    }
    {
      int kpf = kt + 3; if (kpf > NKD-1) kpf = NKD-1;
      DN_PF(B, kpf);
      COMPUTE(As1, Bs1);
      WAITV(8);
      DN_CVW(A, Bs0);
      WAITV(4);
      WAITL();
      BAR();
      DN_GLDA(As1, kpf);
    }
  }
  WAITV(0);
  WAITL();

  const int rsub = (lane >> 4) * 4;
  const int csub = lane & 15;
#pragma unroll
  for (int mi = 0; mi < 4; ++mi)
#pragma unroll
    for (int j = 0; j < 4; ++j) {
      int rl = wr + mi*16 + rsub + j;
      if (m0 + rl < cnt) {
        size_t orow = (size_t)(off + m0 + rl) * H_ + n0 + wc + csub;
#pragma unroll
        for (int cg = 0; cg < 2; ++cg)
          rowbuf[orow + cg*16] = acc[mi][cg][j];
      }
    }
#undef DN_PF
#undef DN_CVW
#undef DN_CVW1
#undef DN_GLDA
}

// ---------------- phase 4: weighted combine ----------------
__global__ void combine_kernel(const float* __restrict__ ew, const int* __restrict__ row_of,
                               const float* __restrict__ rowbuf, float* __restrict__ out) {
  int idx = blockIdx.x * 256 + threadIdx.x;   // over B_*H_/4
  int t  = idx >> 9;                          // H_/4 = 512
  int h4 = idx & 511;
  float w0 = ew[t*2+0], w1 = ew[t*2+1];
  int r0 = row_of[t*2+0], r1 = row_of[t*2+1];
  float4 a = *(const float4*)(rowbuf + (size_t)r0*H_ + h4*4);
  float4 b = *(const float4*)(rowbuf + (size_t)r1*H_ + h4*4);
  float4 o;
  o.x = w0*a.x + w1*b.x; o.y = w0*a.y + w1*b.y;
  o.z = w0*a.z + w1*b.z; o.w = w0*a.w + w1*b.w;
  *(float4*)(out + (size_t)idx*4) = o;
}

extern "C" void kernel_launch(void* const* d_in, const int* in_sizes, int n_in,
                              void* d_out, int out_size, void* d_ws, size_t ws_size,
                              hipStream_t stream) {
  const float* x   = (const float*)d_in[0];
  const int*   ids = (const int*)d_in[1];
  const float* ew  = (const float*)d_in[2];
  const float* gw  = (const float*)d_in[3];
  const float* uw  = (const float*)d_in[4];
  const float* dwn = (const float*)d_in[5];
  float* out = (float*)d_out;

  char* ws = (char*)d_ws;
  int* counts  = (int*)ws;          // 8
  int* offsets = counts + 8;        // 8
  int* tlist   = offsets + 8;       // NROWS
  int* row_of  = tlist + NROWS;     // NROWS
  int* tile_e  = row_of + NROWS;    // MAXT
  int* tile_m  = tile_e + MAXT;     // MAXT
  __bf16* xb   = (__bf16*)(ws + 32768);
  __bf16* act  = (__bf16*)(ws + 32768 + (size_t)B_*H_*2);
  float* rowbuf = (float*)(ws + 32768 + (size_t)B_*H_*2 + (size_t)NROWS*I_*2);

  hipFuncSetAttribute(reinterpret_cast<const void*>(&gateup_kernel),
                      hipFuncAttributeMaxDynamicSharedMemorySize, 49152);
  hipFuncSetAttribute(reinterpret_cast<const void*>(&down_kernel),
                      hipFuncAttributeMaxDynamicSharedMemorySize, 49152);

  cvtx_kernel<<<B_*H_/(256*8), 256, 0, stream>>>(x, xb);
  route_kernel<<<1, 256, 0, stream>>>(ids, counts, offsets, tlist, row_of, tile_e, tile_m);

  gateup_kernel<<<MAXT*NYG, 256, 49152, stream>>>(xb, gw, uw, counts, offsets, tlist,
                                                  tile_e, tile_m, act);

  down_kernel<<<MAXT*NYD, 256, 49152, stream>>>(act, dwn, counts, offsets,
                                                tile_e, tile_m, rowbuf);

  combine_kernel<<<(B_*H_/4)/256, 256, 0, stream>>>(ew, row_of, rowbuf, out);
}

// Round 11
// 419.944 us; speedup vs baseline: 1.9224x; 1.0210x over previous
//
#include <hip/hip_runtime.h>
#include <hip/hip_bf16.h>

#define E_ 8
#define H_ 2048
#define I_ 5632
#define B_ 1024
#define K_ 2
#define NROWS (B_*K_)

#define BM 128
#define BN 64
#define BK 64
#define MAXT 24           // sum_e ceil(cnt_e/128) <= 16 + 8
#define NKG (H_/BK)       // 32
#define NKD (I_/BK)       // 88
#define NYG (I_/BN)       // 88
#define NYD (H_/BN)       // 32

typedef __attribute__((ext_vector_type(8))) __bf16 bf16x8;
typedef __attribute__((ext_vector_type(4))) float f32x4;

union BF4 { __bf16 b[4]; uint2 q; };
union BF8 { __bf16 b[8]; uint4 q; };

__device__ __forceinline__ void gld_lds16(const void* g, void* l) {
  __builtin_amdgcn_global_load_lds(
      (const __attribute__((address_space(1))) void*)g,
      (__attribute__((address_space(3))) void*)l, 16, 0, 0);
}

#define GLOAD4(dst, ptr) asm volatile("global_load_dwordx4 %0, %1, off" : "=v"(dst) : "v"(ptr))
#define WAITV(N) do { asm volatile("s_waitcnt vmcnt(" #N ")" ::: "memory"); __builtin_amdgcn_sched_barrier(0); } while(0)
#define WAITL()  do { asm volatile("s_waitcnt lgkmcnt(0)" ::: "memory"); __builtin_amdgcn_sched_barrier(0); } while(0)
#define BAR()    __builtin_amdgcn_s_barrier()

// bank-spread swizzle (verified R8: conflicts 5.46e7 -> 7.8e6)
#define MSK(c) (((c)&7) ^ (((c)>>2)&7))

// ---------------- phase 0: x (f32) -> xb (bf16) ----------------
__global__ void cvtx_kernel(const float* __restrict__ x, __bf16* __restrict__ xb) {
  int i = (blockIdx.x * 256 + threadIdx.x) * 8;
  float4 a = *(const float4*)(x + i);
  float4 b = *(const float4*)(x + i + 4);
  BF8 r;
  r.b[0] = (__bf16)a.x; r.b[1] = (__bf16)a.y; r.b[2] = (__bf16)a.z; r.b[3] = (__bf16)a.w;
  r.b[4] = (__bf16)b.x; r.b[5] = (__bf16)b.y; r.b[6] = (__bf16)b.z; r.b[7] = (__bf16)b.w;
  *(uint4*)(xb + i) = r.q;
}

// ---------------- phase 1: routing + dense tile list ----------------
__global__ void route_kernel(const int* __restrict__ ids,
                             int* __restrict__ counts, int* __restrict__ offsets,
                             int* __restrict__ tlist, int* __restrict__ row_of,
                             int* __restrict__ tile_e, int* __restrict__ tile_m) {
  __shared__ int sc[E_], sp[E_], so[E_];
  int t = threadIdx.x;
  if (t < E_) { sc[t] = 0; sp[t] = 0; }
  __syncthreads();
  for (int idx = t; idx < NROWS; idx += 256) atomicAdd(&sc[ids[idx]], 1);
  __syncthreads();
  if (t == 0) {
    int acc = 0;
    for (int e = 0; e < E_; ++e) { so[e] = acc; acc += sc[e]; }
    int nt = 0;
    for (int e = 0; e < E_; ++e)
      for (int m0 = 0; m0 < sc[e]; m0 += BM) { tile_e[nt] = e; tile_m[nt] = m0; ++nt; }
    for (; nt < MAXT; ++nt) { tile_e[nt] = 0; tile_m[nt] = 0x7FFFFFFF; }
  }
  __syncthreads();
  for (int idx = t; idx < NROWS; idx += 256) {
    int e = ids[idx];
    int slot = atomicAdd(&sp[e], 1);
    int row = so[e] + slot;
    tlist[row] = idx / K_;
    row_of[idx] = row;
  }
  if (t < E_) { counts[t] = sc[t]; offsets[t] = so[t]; }
}

// ---------------- phase 2: gate+up dual GEMM + SiLU (bf16 act) ----------------
// 48 KB LDS: A DOUBLE-buffered (GLDA keeps full-phase slack) + B SINGLE-
// buffered (filled from regs PF'd a phase ahead) -> 3 blocks/CU.
// Per-wave steady outstanding = PF:8 + glda:4 = 12; counted waits only.
__global__ __launch_bounds__(256, 3) void gateup_kernel(
    const __bf16* __restrict__ xb, const float* __restrict__ gw,
    const float* __restrict__ uw, const int* __restrict__ counts,
    const int* __restrict__ offsets, const int* __restrict__ tlist,
    const int* __restrict__ tile_e, const int* __restrict__ tile_m,
    __bf16* __restrict__ act)
{
  extern __shared__ char smem[];
  char* As0 = smem;                 // 16384 (128 rows x 128B, swizzled)
  char* As1 = smem + 16384;
  char* Bg  = smem + 32768;         // 8192 (64 cols x 128B, swizzled), single
  char* Bu  = smem + 40960;

  const int id = blockIdx.x;                  // [0, 2112)
  const int w  = (id & 7) * 264 + (id >> 3);  // XCD chunking (2112 = 8*264)
  const int tt = w % MAXT;                    // panel sharers adjacent -> same XCD
  const int ny = w / MAXT;                    // [0, 88)
  const int e  = tile_e[tt];
  const int m0 = tile_m[tt];
  const int cnt = counts[e];
  if (m0 >= cnt) return;
  const int off = offsets[e];
  const int n0 = ny * BN;

  const int tid  = threadIdx.x;
  const int lane = tid & 63;
  const int wave = tid >> 6;         // 0..3
  const int wr = (wave >> 1) * 64;   // 0,64
  const int wc = (wave & 1) * 32;    // 0,32

  // ---- A staging: 4 granules/thread, LDS linear, source slot-swizzled
  const __bf16* asrc0; const __bf16* asrc1; const __bf16* asrc2; const __bf16* asrc3;
  int ad0, ad1, ad2, ad3;
  {
    const __bf16* s[4]; int d[4];
#pragma unroll
    for (int i = 0; i < 4; ++i) {
      int f = i*256 + tid;
      int r = f >> 3, cs = f & 7;
      int rr = m0 + r; if (rr >= cnt) rr = cnt - 1;
      int tok = tlist[off + rr];
      s[i] = xb + (size_t)tok * H_ + ((cs ^ (r & 7)) << 3);
      d[i] = f * 16;
    }
    asrc0=s[0]; asrc1=s[1]; asrc2=s[2]; asrc3=s[3];
    ad0=d[0]; ad1=d[1]; ad2=d[2]; ad3=d[3];
  }

  // ---- B staging: thread owns cols 4cq..4cq+3, k-rows kb..kb+3 (dwordx4)
  const int cq = tid & 15;
  const int kb = (tid >> 4) * 4;     // 0..60
  const float* pg0 = gw + ((size_t)e*H_ + kb + 0)*I_ + n0 + 4*cq;
  const float* pg1 = gw + ((size_t)e*H_ + kb + 1)*I_ + n0 + 4*cq;
  const float* pg2 = gw + ((size_t)e*H_ + kb + 2)*I_ + n0 + 4*cq;
  const float* pg3 = gw + ((size_t)e*H_ + kb + 3)*I_ + n0 + 4*cq;
  const float* pu0 = uw + ((size_t)e*H_ + kb + 0)*I_ + n0 + 4*cq;
  const float* pu1 = uw + ((size_t)e*H_ + kb + 1)*I_ + n0 + 4*cq;
  const float* pu2 = uw + ((size_t)e*H_ + kb + 2)*I_ + n0 + 4*cq;
  const float* pu3 = uw + ((size_t)e*H_ + kb + 3)*I_ + n0 + 4*cq;
  const int slot = kb >> 3;
  const int half = (kb & 4) << 1;    // 0 or 8
  int bw0, bw1, bw2, bw3;
  {
    int b[4];
#pragma unroll
    for (int i = 0; i < 4; ++i) {
      int c = 4*cq + i;
      b[i] = c*128 + ((slot ^ MSK(c)) << 4) + half;
    }
    bw0=b[0]; bw1=b[1]; bw2=b[2]; bw3=b[3];
  }

  // single weight reg set: CVW reads it, PF refills right after (wave-serial WAR)
  f32x4 vg_0,vg_1,vg_2,vg_3, vu_0,vu_1,vu_2,vu_3;

  f32x4 accg[4][2], accu[4][2];
#pragma unroll
  for (int i = 0; i < 4; ++i)
#pragma unroll
    for (int j = 0; j < 2; ++j) {
      accg[i][j] = (f32x4){0.f,0.f,0.f,0.f};
      accu[i][j] = (f32x4){0.f,0.f,0.f,0.f};
    }

  auto COMPUTE = [&](const char* Ab) {
    __builtin_amdgcn_s_setprio(1);
#pragma unroll
    for (int kk = 0; kk < 2; ++kk) {
      const int ks = kk*4 + (lane >> 4);
      const int r0 = wr + (lane & 15);
      const int swa = (ks ^ (r0 & 7)) << 4;
      bf16x8 a0 = *(const bf16x8*)(Ab + (r0 +  0)*128 + swa);
      bf16x8 a1 = *(const bf16x8*)(Ab + (r0 + 16)*128 + swa);
      bf16x8 a2 = *(const bf16x8*)(Ab + (r0 + 32)*128 + swa);
      bf16x8 a3 = *(const bf16x8*)(Ab + (r0 + 48)*128 + swa);
      const int c0 = wc + (lane & 15);
      const int swb0 = (ks ^ MSK(c0)) << 4;
      const int swb1 = swb0 ^ (4 << 4);     // MSK(c+16) = MSK(c) ^ 4
      bf16x8 g0 = *(const bf16x8*)(Bg + c0*128 + swb0);
      bf16x8 g1 = *(const bf16x8*)(Bg + (c0+16)*128 + swb1);
      bf16x8 u0 = *(const bf16x8*)(Bu + c0*128 + swb0);
      bf16x8 u1 = *(const bf16x8*)(Bu + (c0+16)*128 + swb1);
      accg[0][0] = __builtin_amdgcn_mfma_f32_16x16x32_bf16(a0, g0, accg[0][0], 0,0,0);
      accg[1][0] = __builtin_amdgcn_mfma_f32_16x16x32_bf16(a1, g0, accg[1][0], 0,0,0);
      accg[2][0] = __builtin_amdgcn_mfma_f32_16x16x32_bf16(a2, g0, accg[2][0], 0,0,0);
      accg[3][0] = __builtin_amdgcn_mfma_f32_16x16x32_bf16(a3, g0, accg[3][0], 0,0,0);
      accg[0][1] = __builtin_amdgcn_mfma_f32_16x16x32_bf16(a0, g1, accg[0][1], 0,0,0);
      accg[1][1] = __builtin_amdgcn_mfma_f32_16x16x32_bf16(a1, g1, accg[1][1], 0,0,0);
      accg[2][1] = __builtin_amdgcn_mfma_f32_16x16x32_bf16(a2, g1, accg[2][1], 0,0,0);
      accg[3][1] = __builtin_amdgcn_mfma_f32_16x16x32_bf16(a3, g1, accg[3][1], 0,0,0);
      accu[0][0] = __builtin_amdgcn_mfma_f32_16x16x32_bf16(a0, u0, accu[0][0], 0,0,0);
      accu[1][0] = __builtin_amdgcn_mfma_f32_16x16x32_bf16(a1, u0, accu[1][0], 0,0,0);
      accu[2][0] = __builtin_amdgcn_mfma_f32_16x16x32_bf16(a2, u0, accu[2][0], 0,0,0);
      accu[3][0] = __builtin_amdgcn_mfma_f32_16x16x32_bf16(a3, u0, accu[3][0], 0,0,0);
      accu[0][1] = __builtin_amdgcn_mfma_f32_16x16x32_bf16(a0, u1, accu[0][1], 0,0,0);
      accu[1][1] = __builtin_amdgcn_mfma_f32_16x16x32_bf16(a1, u1, accu[1][1], 0,0,0);
      accu[2][1] = __builtin_amdgcn_mfma_f32_16x16x32_bf16(a2, u1, accu[2][1], 0,0,0);
      accu[3][1] = __builtin_amdgcn_mfma_f32_16x16x32_bf16(a3, u1, accu[3][1], 0,0,0);
    }
    __builtin_amdgcn_s_setprio(0);
  };

#define GU_PF(KPF) do { size_t o_ = (size_t)(KPF)*(size_t)BK*(size_t)I_; \
    GLOAD4(vg_0, pg0+o_); GLOAD4(vu_0, pu0+o_); \
    GLOAD4(vg_1, pg1+o_); GLOAD4(vu_1, pu1+o_); \
    GLOAD4(vg_2, pg2+o_); GLOAD4(vu_2, pu2+o_); \
    GLOAD4(vg_3, pg3+o_); GLOAD4(vu_3, pu3+o_); } while(0)

#define GU_CVW1(BB, V0, V1, V2, V3, BWI, I) do { BF4 p_; \
    p_.b[0]=(__bf16)V0[I]; p_.b[1]=(__bf16)V1[I]; p_.b[2]=(__bf16)V2[I]; p_.b[3]=(__bf16)V3[I]; \
    *(uint2*)((BB)+BWI) = p_.q; } while(0)

#define GU_CVW() do { \
    GU_CVW1(Bg, vg_0, vg_1, vg_2, vg_3, bw0, 0); \
    GU_CVW1(Bg, vg_0, vg_1, vg_2, vg_3, bw1, 1); \
    GU_CVW1(Bg, vg_0, vg_1, vg_2, vg_3, bw2, 2); \
    GU_CVW1(Bg, vg_0, vg_1, vg_2, vg_3, bw3, 3); \
    GU_CVW1(Bu, vu_0, vu_1, vu_2, vu_3, bw0, 0); \
    GU_CVW1(Bu, vu_0, vu_1, vu_2, vu_3, bw1, 1); \
    GU_CVW1(Bu, vu_0, vu_1, vu_2, vu_3, bw2, 2); \
    GU_CVW1(Bu, vu_0, vu_1, vu_2, vu_3, bw3, 3); } while(0)

#define GU_GLDA(DST, KPF) do { size_t k_ = (size_t)(KPF)*(size_t)BK; \
    gld_lds16(asrc0 + k_, (DST)+ad0); gld_lds16(asrc1 + k_, (DST)+ad1); \
    gld_lds16(asrc2 + k_, (DST)+ad2); gld_lds16(asrc3 + k_, (DST)+ad3); } while(0)

  // ---- prologue: B(0)->LDS; A(0)->As0; PF(1)+glda(1->As1) in flight
  GU_PF(0);
  WAITV(0);
  GU_CVW();             // B(0)
  GU_GLDA(As0, 0);
  WAITV(0);             // A(0) landed (own)
  GU_PF(1);             // 8
  GU_GLDA(As1, 1);      // -> 12
  WAITL();
  BAR();                // B(0)+A(0) visible to all

#pragma unroll 1
  for (int kt = 0; kt < NKG; kt += 2) {
    { // even kt: A from As0; B holds kt. Regs hold kt+1; glda(kt+1) in flight.
      int kpf = kt + 2; if (kpf > NKG-1) kpf = NKG-1;
      COMPUTE(As0);
      WAITV(4);                    // retire PF(kt+1) [oldest 8]; keep glda(kt+1)
      WAITL();
      BAR();                       // all waves done reading B(kt) & As0
      GU_CVW();                    // B <- kt+1
      GU_PF(kpf);                  // -> glda4 + PF8 = 12
      WAITV(8);                    // retire glda(kt+1): had full-phase slack
      WAITL();
      BAR();                       // B(kt+1) + As1=A(kt+1) visible
      GU_GLDA(As0, kpf);           // -> 12; consumed at kt+2
    }
    { // odd kt+1: A from As1; B holds kt+1. Regs hold kt+2; glda(kt+2) in flight.
      int kpf = kt + 3; if (kpf > NKG-1) kpf = NKG-1;
      COMPUTE(As1);
      WAITV(4);
      WAITL();
      BAR();
      GU_CVW();                    // B <- kt+2
      GU_PF(kpf);
      WAITV(8);
      WAITL();
      BAR();
      GU_GLDA(As1, kpf);
    }
  }
  WAITV(0);
  WAITL();

  // ---- epilogue: SiLU(g)*u -> bf16 act
  const int rsub = (lane >> 4) * 4;
  const int csub = lane & 15;
#pragma unroll
  for (int mi = 0; mi < 4; ++mi)
#pragma unroll
    for (int j = 0; j < 4; ++j) {
      int rl = wr + mi*16 + rsub + j;
      if (m0 + rl < cnt) {
        size_t orow = (size_t)(off + m0 + rl) * I_ + n0 + wc + csub;
#pragma unroll
        for (int cg = 0; cg < 2; ++cg) {
          float g = accg[mi][cg][j];
          float u = accu[mi][cg][j];
          float sg = g / (1.0f + __expf(-g));
          act[orow + cg*16] = (__bf16)(sg * u);
        }
      }
    }
#undef GU_PF
#undef GU_CVW
#undef GU_CVW1
#undef GU_GLDA
}

// ---------------- phase 3: down GEMM -> rowbuf (f32) ----------------
// R8-proven: 48 KB LDS -> 3 blocks/CU. Steady outstanding 8 (PF:4 + GLDA:4).
__global__ __launch_bounds__(256, 3) void down_kernel(
    const __bf16* __restrict__ act, const float* __restrict__ dw,
    const int* __restrict__ counts, const int* __restrict__ offsets,
    const int* __restrict__ tile_e, const int* __restrict__ tile_m,
    float* __restrict__ rowbuf)
{
  extern __shared__ char smem[];
  char* As0 = smem;
  char* As1 = smem + 16384;
  char* Bs0 = smem + 32768;
  char* Bs1 = smem + 40960;

  const int id = blockIdx.x;                  // [0, 768)
  const int w  = (id & 7) * 96 + (id >> 3);   // 768 = 8*96
  const int tt = w % MAXT;
  const int ny = w / MAXT;                    // [0, 32)
  const int e  = tile_e[tt];
  const int m0 = tile_m[tt];
  const int cnt = counts[e];
  if (m0 >= cnt) return;
  const int off = offsets[e];
  const int n0 = ny * BN;

  const int tid  = threadIdx.x;
  const int lane = tid & 63;
  const int wave = tid >> 6;
  const int wr = (wave >> 1) * 64;
  const int wc = (wave & 1) * 32;

  const __bf16* asrc0; const __bf16* asrc1; const __bf16* asrc2; const __bf16* asrc3;
  int ad0, ad1, ad2, ad3;
  {
    const __bf16* s[4]; int d[4];
#pragma unroll
    for (int i = 0; i < 4; ++i) {
      int f = i*256 + tid;
      int r = f >> 3, cs = f & 7;
      int rr = m0 + r; if (rr >= cnt) rr = cnt - 1;
      s[i] = act + (size_t)(off + rr) * I_ + ((cs ^ (r & 7)) << 3);
      d[i] = f * 16;
    }
    asrc0=s[0]; asrc1=s[1]; asrc2=s[2]; asrc3=s[3];
    ad0=d[0]; ad1=d[1]; ad2=d[2]; ad3=d[3];
  }

  const int cq = tid & 15;
  const int kb = (tid >> 4) * 4;
  const float* pd0 = dw + ((size_t)e*I_ + kb + 0)*H_ + n0 + 4*cq;
  const float* pd1 = dw + ((size_t)e*I_ + kb + 1)*H_ + n0 + 4*cq;
  const float* pd2 = dw + ((size_t)e*I_ + kb + 2)*H_ + n0 + 4*cq;
  const float* pd3 = dw + ((size_t)e*I_ + kb + 3)*H_ + n0 + 4*cq;
  const int slot = kb >> 3;
  const int half = (kb & 4) << 1;
  int bw0, bw1, bw2, bw3;
  {
    int b[4];
#pragma unroll
    for (int i = 0; i < 4; ++i) {
      int c = 4*cq + i;
      b[i] = c*128 + ((slot ^ MSK(c)) << 4) + half;
    }
    bw0=b[0]; bw1=b[1]; bw2=b[2]; bw3=b[3];
  }

  f32x4 vdA_0,vdA_1,vdA_2,vdA_3;
  f32x4 vdB_0,vdB_1,vdB_2,vdB_3;

  f32x4 acc[4][2];
#pragma unroll
  for (int i = 0; i < 4; ++i)
#pragma unroll
    for (int j = 0; j < 2; ++j) acc[i][j] = (f32x4){0.f,0.f,0.f,0.f};

  auto COMPUTE = [&](const char* Ab, const char* Bb) {
    __builtin_amdgcn_s_setprio(1);
#pragma unroll
    for (int kk = 0; kk < 2; ++kk) {
      const int ks = kk*4 + (lane >> 4);
      const int r0 = wr + (lane & 15);
      const int swa = (ks ^ (r0 & 7)) << 4;
      bf16x8 a0 = *(const bf16x8*)(Ab + (r0 +  0)*128 + swa);
      bf16x8 a1 = *(const bf16x8*)(Ab + (r0 + 16)*128 + swa);
      bf16x8 a2 = *(const bf16x8*)(Ab + (r0 + 32)*128 + swa);
      bf16x8 a3 = *(const bf16x8*)(Ab + (r0 + 48)*128 + swa);
      const int c0 = wc + (lane & 15);
      const int swb0 = (ks ^ MSK(c0)) << 4;
      const int swb1 = swb0 ^ (4 << 4);
      bf16x8 b0 = *(const bf16x8*)(Bb + c0*128 + swb0);
      bf16x8 b1 = *(const bf16x8*)(Bb + (c0+16)*128 + swb1);
      acc[0][0] = __builtin_amdgcn_mfma_f32_16x16x32_bf16(a0, b0, acc[0][0], 0,0,0);
      acc[1][0] = __builtin_amdgcn_mfma_f32_16x16x32_bf16(a1, b0, acc[1][0], 0,0,0);
      acc[2][0] = __builtin_amdgcn_mfma_f32_16x16x32_bf16(a2, b0, acc[2][0], 0,0,0);
      acc[3][0] = __builtin_amdgcn_mfma_f32_16x16x32_bf16(a3, b0, acc[3][0], 0,0,0);
      acc[0][1] = __builtin_amdgcn_mfma_f32_16x16x32_bf16(a0, b1, acc[0][1], 0,0,0);
      acc[1][1] = __builtin_amdgcn_mfma_f32_16x16x32_bf16(a1, b1, acc[1][1], 0,0,0);
      acc[2][1] = __builtin_amdgcn_mfma_f32_16x16x32_bf16(a2, b1, acc[2][1], 0,0,0);
      acc[3][1] = __builtin_amdgcn_mfma_f32_16x16x32_bf16(a3, b1, acc[3][1], 0,0,0);
    }
    __builtin_amdgcn_s_setprio(0);
  };

#define DN_PF(S, KPF) do { size_t o_ = (size_t)(KPF)*(size_t)BK*(size_t)H_; \
    GLOAD4(vd##S##_0, pd0+o_); GLOAD4(vd##S##_1, pd1+o_); \
    GLOAD4(vd##S##_2, pd2+o_); GLOAD4(vd##S##_3, pd3+o_); } while(0)

#define DN_CVW1(BB, V0, V1, V2, V3, BWI, I) do { BF4 p_; \
    p_.b[0]=(__bf16)V0[I]; p_.b[1]=(__bf16)V1[I]; p_.b[2]=(__bf16)V2[I]; p_.b[3]=(__bf16)V3[I]; \
    *(uint2*)((BB)+BWI) = p_.q; } while(0)

#define DN_CVW(S, BB) do { \
    DN_CVW1(BB, vd##S##_0, vd##S##_1, vd##S##_2, vd##S##_3, bw0, 0); \
    DN_CVW1(BB, vd##S##_0, vd##S##_1, vd##S##_2, vd##S##_3, bw1, 1); \
    DN_CVW1(BB, vd##S##_0, vd##S##_1, vd##S##_2, vd##S##_3, bw2, 2); \
    DN_CVW1(BB, vd##S##_0, vd##S##_1, vd##S##_2, vd##S##_3, bw3, 3); } while(0)

#define DN_GLDA(DST, KPF) do { size_t k_ = (size_t)(KPF)*(size_t)BK; \
    gld_lds16(asrc0 + k_, (DST)+ad0); gld_lds16(asrc1 + k_, (DST)+ad1); \
    gld_lds16(asrc2 + k_, (DST)+ad2); gld_lds16(asrc3 + k_, (DST)+ad3); } while(0)

  DN_PF(A, 0);          // 4
  DN_GLDA(As0, 0);      // -> 8
  WAITV(4);             // drain PF(0)
  DN_CVW(A, Bs0);
  DN_PF(B, 1);          // -> 8
  DN_GLDA(As1, 1);      // -> 12
  WAITV(8);             // drain GLDA(0); PF(1)+GLDA(1)=8 left
  WAITL();
  BAR();

#pragma unroll 1
  for (int kt = 0; kt < NKD; kt += 2) {
    {
      int kpf = kt + 2; if (kpf > NKD-1) kpf = NKD-1;
      DN_PF(A, kpf);               // -> 12
      COMPUTE(As0, Bs0);
      WAITV(8);                    // drain PF_B(kt+1)
      DN_CVW(B, Bs1);
      WAITV(4);                    // drain GLDA(kt+1)
      WAITL();
      BAR();
      DN_GLDA(As0, kpf);           // -> 8
    }
    {
      int kpf = kt + 3; if (kpf > NKD-1) kpf = NKD-1;
      DN_PF(B, kpf);
      COMPUTE(As1, Bs1);
      WAITV(8);
      DN_CVW(A, Bs0);
      WAITV(4);
      WAITL();
      BAR();
      DN_GLDA(As1, kpf);
    }
  }
  WAITV(0);
  WAITL();

  const int rsub = (lane >> 4) * 4;
  const int csub = lane & 15;
#pragma unroll
  for (int mi = 0; mi < 4; ++mi)
#pragma unroll
    for (int j = 0; j < 4; ++j) {
      int rl = wr + mi*16 + rsub + j;
      if (m0 + rl < cnt) {
        size_t orow = (size_t)(off + m0 + rl) * H_ + n0 + wc + csub;
#pragma unroll
        for (int cg = 0; cg < 2; ++cg)
          rowbuf[orow + cg*16] = acc[mi][cg][j];
      }
    }
#undef DN_PF
#undef DN_CVW
#undef DN_CVW1
#undef DN_GLDA
}

// ---------------- phase 4: weighted combine ----------------
__global__ void combine_kernel(const float* __restrict__ ew, const int* __restrict__ row_of,
                               const float* __restrict__ rowbuf, float* __restrict__ out) {
  int idx = blockIdx.x * 256 + threadIdx.x;   // over B_*H_/4
  int t  = idx >> 9;                          // H_/4 = 512
  int h4 = idx & 511;
  float w0 = ew[t*2+0], w1 = ew[t*2+1];
  int r0 = row_of[t*2+0], r1 = row_of[t*2+1];
  float4 a = *(const float4*)(rowbuf + (size_t)r0*H_ + h4*4);
  float4 b = *(const float4*)(rowbuf + (size_t)r1*H_ + h4*4);
  float4 o;
  o.x = w0*a.x + w1*b.x; o.y = w0*a.y + w1*b.y;
  o.z = w0*a.z + w1*b.z; o.w = w0*a.w + w1*b.w;
  *(float4*)(out + (size_t)idx*4) = o;
}

extern "C" void kernel_launch(void* const* d_in, const int* in_sizes, int n_in,
                              void* d_out, int out_size, void* d_ws, size_t ws_size,
                              hipStream_t stream) {
  const float* x   = (const float*)d_in[0];
  const int*   ids = (const int*)d_in[1];
  const float* ew  = (const float*)d_in[2];
  const float* gw  = (const float*)d_in[3];
  const float* uw  = (const float*)d_in[4];
  const float* dwn = (const float*)d_in[5];
  float* out = (float*)d_out;

  char* ws = (char*)d_ws;
  int* counts  = (int*)ws;          // 8
  int* offsets = counts + 8;        // 8
  int* tlist   = offsets + 8;       // NROWS
  int* row_of  = tlist + NROWS;     // NROWS
  int* tile_e  = row_of + NROWS;    // MAXT
  int* tile_m  = tile_e + MAXT;     // MAXT
  __bf16* xb   = (__bf16*)(ws + 32768);
  __bf16* act  = (__bf16*)(ws + 32768 + (size_t)B_*H_*2);
  float* rowbuf = (float*)(ws + 32768 + (size_t)B_*H_*2 + (size_t)NROWS*I_*2);

  hipFuncSetAttribute(reinterpret_cast<const void*>(&gateup_kernel),
                      hipFuncAttributeMaxDynamicSharedMemorySize, 49152);
  hipFuncSetAttribute(reinterpret_cast<const void*>(&down_kernel),
                      hipFuncAttributeMaxDynamicSharedMemorySize, 49152);

  cvtx_kernel<<<B_*H_/(256*8), 256, 0, stream>>>(x, xb);
  route_kernel<<<1, 256, 0, stream>>>(ids, counts, offsets, tlist, row_of, tile_e, tile_m);

  gateup_kernel<<<MAXT*NYG, 256, 49152, stream>>>(xb, gw, uw, counts, offsets, tlist,
                                                  tile_e, tile_m, act);

  down_kernel<<<MAXT*NYD, 256, 49152, stream>>>(act, dwn, counts, offsets,
                                                tile_e, tile_m, rowbuf);

  combine_kernel<<<(B_*H_/4)/256, 256, 0, stream>>>(ew, row_of, rowbuf, out);
}